// Round 8
// baseline (3777.614 us; speedup 1.0000x reference)
//
#include <hip/hip_runtime.h>
#include <hip/hip_bf16.h>

// GRU: SEQ=64, BATCH=64, HID=EMB=512, VOCAB=10000, LAYERS=2
// Outputs: logits (64,64,10000) f32 then h_final (2,64,512) f32, concat flat.

#define SEQ 64
#define NPART 32   // worker blocks (elected on ONE XCD; its L2 = coherence point)

typedef short s16x8 __attribute__((ext_vector_type(8)));   // 8 bf16 (4 VGPRs)
typedef float f32x4 __attribute__((ext_vector_type(4)));
typedef unsigned long long ull;

static __device__ __forceinline__ unsigned short f2bf(float f){
    unsigned int u = __float_as_uint(f);
    return (unsigned short)((u + 0x7FFFu + ((u >> 16) & 1u)) >> 16);  // RNE
}
static __device__ __forceinline__ float bf2f(unsigned short s){
    return __uint_as_float(((unsigned int)s) << 16);
}
static __device__ __forceinline__ float sigm(float x){
    return __fdividef(1.0f, 1.0f + __expf(-x));
}
static __device__ __forceinline__ float tanh_fast(float x){
    float ax = fabsf(x);
    float e = __expf(-2.0f * ax);
    float r = __fdividef(1.0f - e, 1.0f + e);
    return copysignf(r, x);
}
static __device__ __forceinline__ ull pack4bf(const float v[4]){
    union { ull u; unsigned short s[4]; } x;
    x.s[0]=f2bf(v[0]); x.s[1]=f2bf(v[1]); x.s[2]=f2bf(v[2]); x.s[3]=f2bf(v[3]);
    return x.u;
}

// ---------------------------------------------------------------- prep ------
__global__ void prep_kernel(const int* __restrict__ inputs, const float* __restrict__ hidden,
    const float* __restrict__ emb, const float* __restrict__ Wx, const float* __restrict__ Uh,
    const float* __restrict__ Uht, const float* __restrict__ dec_w,
    unsigned short* __restrict__ emb_bf, unsigned short* __restrict__ WxT0,
    unsigned short* __restrict__ UhT0, unsigned short* __restrict__ UhtT0,
    unsigned short* __restrict__ B3T, unsigned short* __restrict__ UhtT1,
    unsigned short* __restrict__ decpad,
    float* __restrict__ HH, unsigned short* __restrict__ HHbf, unsigned int* __restrict__ barzone)
{
    const long long stride = (long long)gridDim.x * blockDim.x;
    const long long t0 = (long long)blockIdx.x * blockDim.x + threadIdx.x;
    for (long long i = t0; i < 4096LL*512; i += stride){
        int r = (int)(i >> 9), k = (int)(i & 511);
        emb_bf[i] = f2bf(emb[(long long)inputs[r]*512 + k]);
    }
    for (long long i = t0; i < 1536LL*512; i += stride){
        int n = (int)(i >> 9), k = (int)(i & 511);
        WxT0[i] = f2bf(Wx[(long long)k*1536 + n]);
    }
    for (long long i = t0; i < 1024LL*512; i += stride){
        int n = (int)(i >> 9), k = (int)(i & 511);
        UhT0[i] = f2bf(Uh[(long long)k*1024 + n]);
    }
    for (long long i = t0; i < 512LL*512; i += stride){
        int n = (int)(i >> 9), k = (int)(i & 511);
        UhtT0[i] = f2bf(Uht[(long long)k*512 + n]);
    }
    for (long long i = t0; i < 1536LL*1024; i += stride){
        int n = (int)(i >> 10), k2 = (int)(i & 1023);
        float v;
        if (k2 < 512) v = Wx[(long long)(512 + k2)*1536 + n];          // Wx[1][k2][n]
        else { int k = k2 - 512; v = (n < 1024) ? Uh[(long long)(512 + k)*1024 + n] : 0.0f; }
        B3T[i] = f2bf(v);
    }
    for (long long i = t0; i < 512LL*512; i += stride){
        int n = (int)(i >> 9), k = (int)(i & 511);
        UhtT1[i] = f2bf(Uht[(long long)(512 + k)*512 + n]);
    }
    for (long long i = t0; i < 10112LL*512; i += stride){
        int n = (int)(i >> 9), k = (int)(i & 511);
        decpad[i] = (n < 10000) ? f2bf(dec_w[(long long)n*512 + k]) : (unsigned short)0;
    }
    for (long long i = t0; i < 65536; i += stride){
        int b = (int)(i >> 10), c = (int)(i & 1023);
        int l = c >> 9, j = c & 511;
        float v = hidden[((long long)l*64 + b)*512 + j];
        HH[i] = v; HHbf[i] = f2bf(v);                                  // HH[b][l*512+j]
    }
    for (long long i = t0; i < 2048; i += stride) barzone[i] = 0u;
}

// ------------------------------------------------- tiled 128x128 bf16 GEMM --
__global__ __launch_bounds__(256) void gemm128(const unsigned short* __restrict__ A,
    const unsigned short* __restrict__ BT, int M, int N, int K, int mode,
    float* __restrict__ outF, unsigned short* __restrict__ outB,
    const float* __restrict__ bias, int Nreal)
{
    __shared__ unsigned short Ash[128*32];
    __shared__ unsigned short Bsh[128*32];
    const int nT = N >> 7;
    const int mb = blockIdx.x / nT, nb = blockIdx.x % nT;
    const int tid = threadIdx.x;
    const int lane = tid & 63, wId = tid >> 6;
    const int wm = wId >> 1, wn = wId & 1;
    const int ln = lane & 15, kg = lane >> 4;
    f32x4 acc[4][4];
    #pragma unroll
    for (int mt = 0; mt < 4; ++mt)
        #pragma unroll
        for (int nt = 0; nt < 4; ++nt) acc[mt][nt] = f32x4{0.f,0.f,0.f,0.f};

    for (int kc = 0; kc < K; kc += 32){
        #pragma unroll
        for (int it = 0; it < 2; ++it){
            int flat = it*256 + tid;
            int row = flat >> 2, kq = flat & 3;
            *(int4*)(&Ash[flat*8]) = *(const int4*)(A + (long long)(mb*128 + row)*K + kc + kq*8);
            *(int4*)(&Bsh[flat*8]) = *(const int4*)(BT + (long long)(nb*128 + row)*K + kc + kq*8);
        }
        __syncthreads();
        s16x8 af[4], bfv[4];
        #pragma unroll
        for (int mt = 0; mt < 4; ++mt) af[mt]  = *(const s16x8*)(&Ash[(wm*64 + mt*16 + ln)*32 + kg*8]);
        #pragma unroll
        for (int nt = 0; nt < 4; ++nt) bfv[nt] = *(const s16x8*)(&Bsh[(wn*64 + nt*16 + ln)*32 + kg*8]);
        #pragma unroll
        for (int mt = 0; mt < 4; ++mt)
            #pragma unroll
            for (int nt = 0; nt < 4; ++nt)
                acc[mt][nt] = __builtin_amdgcn_mfma_f32_16x16x32_bf16(af[mt], bfv[nt], acc[mt][nt], 0, 0, 0);
        __syncthreads();
    }
    #pragma unroll
    for (int mt = 0; mt < 4; ++mt)
        #pragma unroll
        for (int nt = 0; nt < 4; ++nt)
            #pragma unroll
            for (int r = 0; r < 4; ++r){
                int row = mb*128 + wm*64 + mt*16 + kg*4 + r;   // C/D: col=lane&15, row=(lane>>4)*4+reg
                int col = nb*128 + wn*64 + nt*16 + ln;
                float v = acc[mt][nt][r];
                if (mode == 0){
                    outB[(long long)row*N + col] = f2bf(v);
                } else {
                    if (col < Nreal) outF[(long long)row*Nreal + col] = v + bias[col];
                }
            }
}

// -------------------------------------------------------- persistent GRU ----
// Workers share one XCD -> plain (cached) loads/stores through the XCD L2.
// Barrier flags in MALL via sc0sc1 (round-6/7-proven); buffer_inv (L1-only)
// after each barrier keeps plain loads L2-fresh. Poll bounded (hang-proof).
static __device__ __forceinline__ void gsync(unsigned int* flags, int rank, unsigned gen){
    asm volatile("s_waitcnt vmcnt(0)" ::: "memory");   // plain stores -> L2 visible
    __syncthreads();
    if (threadIdx.x < 64){
        if (threadIdx.x == 0){
            asm volatile("global_store_dword %0, %1, off sc0 sc1"
                         :: "v"(flags + rank*32), "v"(gen) : "memory");
        }
        const unsigned int* p = flags + (threadIdx.x & (NPART-1))*32;
        unsigned v; int it = 0;
        do {
            asm volatile("global_load_dword %0, %1, off sc0 sc1\n\ts_waitcnt vmcnt(0)"
                         : "=v"(v) : "v"(p) : "memory");
        } while (__ballot(v >= gen) != ~0ull && ++it < (1 << 20));
    }
    __syncthreads();
    asm volatile("buffer_inv" ::: "memory");           // L1 invalidate (fresh L2 reads)
}

__global__ __launch_bounds__(256, 1) void gru_kernel(
    float* __restrict__ HHf, unsigned short* __restrict__ HHbf,
    const unsigned short* __restrict__ UhT0, const unsigned short* __restrict__ UhtT0,
    const unsigned short* __restrict__ B3T,  const unsigned short* __restrict__ UhtT1,
    const unsigned short* __restrict__ WX0,
    unsigned short* __restrict__ rh0, unsigned short* __restrict__ rh1,
    float* __restrict__ z0, float* __restrict__ z1, float* __restrict__ P3,
    unsigned short* __restrict__ H2bf, const float* __restrict__ b_rzh,
    float* __restrict__ outTail, unsigned int* __restrict__ barzone)
{
    __shared__ __align__(16) char smem[131072];   // 128 KB -> 1 block/CU
    __shared__ int s_rank;
    const int tid = threadIdx.x, lane = tid & 63, wv = tid >> 6;  // 4 waves/block
    const int ln = lane & 15, kg = lane >> 4;

    // ---- elect NPART workers sharing one XCC_ID (1 block/CU -> 32 per XCD)
    if (tid == 0){
        unsigned xcc;
        asm volatile("s_getreg_b32 %0, hwreg(HW_REG_XCC_ID)" : "=s"(xcc));
        unsigned my = (xcc & 15u) + 1u;
        unsigned prev = atomicCAS(barzone + 1, 0u, my);
        unsigned tgt = prev ? prev : my;
        int r = -1;
        if (my == tgt) r = (int)atomicAdd(barzone, 1u);
        s_rank = r;
    }
    __syncthreads();
    const int rank = s_rank;
    if (rank < 0 || rank >= NPART) return;       // non-workers exit

    unsigned int* flags = barzone + 256;
    const int gw = rank*4 + wv;                  // 0..127 wave-job id
    const float* b0 = b_rzh;
    const float* b1 = b_rzh + 1536;
    unsigned gen = 0;

    // roles: S1 = gw<32 (32 jobs x 32n, K=512); S3 = gw in [32,128) (96 x 16n, K=1024)
    //        S2 = gw<32 (32 x 16n, K=512);      S4 = gw in [32,64)  (32 x 16n, K=512)
    const bool roleS1 = (gw < 32);
    const bool roleS4 = (gw >= 32 && gw < 64);
    const int n0A = roleS1 ? gw*32 : (gw - 32)*16;
    const int n0B = roleS1 ? gw*16 : (gw - 32)*16;

    // ---- weights -> registers, loaded ONCE (no cross-wave reuse exists) ----
    s16x8 wA[32];   // S1: [k*2+mt] (K=512, 32n) | S3: [k] (K=1024, 16n)  = 128 VGPR
    s16x8 wB[16];   // S2/S4: [k] (K=512, 16n)                            =  64 VGPR
    if (roleS1){
        #pragma unroll
        for (int k = 0; k < 16; ++k)
            #pragma unroll
            for (int mt = 0; mt < 2; ++mt)
                wA[k*2+mt] = *(const s16x8*)(UhT0 + (n0A + mt*16 + ln)*512 + k*32 + kg*8);
    } else {
        #pragma unroll
        for (int k = 0; k < 32; ++k)
            wA[k] = *(const s16x8*)(B3T + (long long)(n0A + ln)*1024 + k*32 + kg*8);
    }
    if (roleS1){
        #pragma unroll
        for (int k = 0; k < 16; ++k)
            wB[k] = *(const s16x8*)(UhtT0 + (n0B + ln)*512 + k*32 + kg*8);
    } else if (roleS4){
        #pragma unroll
        for (int k = 0; k < 16; ++k)
            wB[k] = *(const s16x8*)(UhtT1 + (n0B + ln)*512 + k*32 + kg*8);
    }
    // per-wave biases
    f32x4 biasA0 = *(const f32x4*)(b0 + n0A + kg*4);
    f32x4 biasA1 = roleS1 ? *(const f32x4*)(b0 + n0A + 16 + kg*4)
                          : *(const f32x4*)(b1 + (n0A < 1024 ? n0A : 0) + kg*4);
    f32x4 biasB  = roleS1 ? *(const f32x4*)(b0 + 1024 + n0B + kg*4)
                          : *(const f32x4*)(b1 + 1024 + (roleS4 ? n0B : 0) + kg*4);

    for (int ss = 0; ss <= SEQ; ++ss){
        // ===================== phase A: S1(ss) || S3(ss-1) ==================
        // stage H -> LDS (pitch 2048, byte ^= (row&7)<<4); blocks 0-7 need h0 only
        if (rank < 8){
            const int4* src = (const int4*)HHbf;
            int4 t[16];
            #pragma unroll
            for (int j = 0; j < 16; ++j){
                const int c = tid + j*256;                 // 0..4095 (64 rows x 64 int4)
                t[j] = src[((c >> 6) << 7) + (c & 63)];
            }
            #pragma unroll
            for (int j = 0; j < 16; ++j){
                const int c = tid + j*256;
                *(int4*)(smem + (((c >> 6)*2048 + (c & 63)*16) ^ (((c >> 6) & 7) << 4))) = t[j];
            }
        } else {
            const int4* src = (const int4*)HHbf;           // full 8192 int4
            int4 t[32];
            #pragma unroll
            for (int j = 0; j < 32; ++j) t[j] = src[tid + j*256];
            #pragma unroll
            for (int j = 0; j < 32; ++j){
                const int c = tid + j*256;
                *(int4*)(smem + ((c*16) ^ (((c >> 7) & 7) << 4))) = t[j];
            }
        }
        __syncthreads();
        if (roleS1){
            if (ss < SEQ){
                const int t = ss;
                ull wxv[2][4];                             // prefetch WX0 (hides L2/HBM)
                #pragma unroll
                for (int mt = 0; mt < 2; ++mt)
                    #pragma unroll
                    for (int nt = 0; nt < 4; ++nt)
                        wxv[mt][nt] = *(const ull*)(WX0 + (long long)(t*64 + nt*16 + ln)*1536
                                                   + n0A + mt*16 + kg*4);
                f32x4 acc[2][4];
                #pragma unroll
                for (int mt = 0; mt < 2; ++mt)
                    #pragma unroll
                    for (int nt = 0; nt < 4; ++nt) acc[mt][nt] = f32x4{0.f,0.f,0.f,0.f};
                #pragma unroll
                for (int k = 0; k < 16; ++k){
                    s16x8 bv[4];
                    #pragma unroll
                    for (int nt = 0; nt < 4; ++nt){
                        const int row = nt*16 + ln;
                        bv[nt] = *(const s16x8*)(smem + ((row*2048 + k*64 + kg*16) ^ ((row & 7) << 4)));
                    }
                    #pragma unroll
                    for (int mt = 0; mt < 2; ++mt)
                        #pragma unroll
                        for (int nt = 0; nt < 4; ++nt)
                            acc[mt][nt] = __builtin_amdgcn_mfma_f32_16x16x32_bf16(wA[k*2+mt], bv[nt], acc[mt][nt], 0, 0, 0);
                }
                #pragma unroll
                for (int mt = 0; mt < 2; ++mt){
                    const int nq = n0A + mt*16 + kg*4;
                    const f32x4 bias = mt ? biasA1 : biasA0;
                    #pragma unroll
                    for (int nt = 0; nt < 4; ++nt){
                        const int b = nt*16 + ln;
                        union { ull u; unsigned short s[4]; } wx; wx.u = wxv[mt][nt];
                        float sg[4];
                        #pragma unroll
                        for (int r = 0; r < 4; ++r)
                            sg[r] = sigm(acc[mt][nt][r] + bf2f(wx.s[r]) + bias[r]);
                        if (nq < 512){
                            union { ull u; unsigned short s[4]; } h;
                            h.u = *(const ull*)(smem + ((b*2048 + nq*2) ^ ((b & 7) << 4)));
                            float rv[4];
                            #pragma unroll
                            for (int r = 0; r < 4; ++r) rv[r] = sg[r] * bf2f(h.s[r]);
                            *(ull*)(rh0 + b*512 + nq) = pack4bf(rv);
                        } else {
                            f32x4 zz = {sg[0], sg[1], sg[2], sg[3]};
                            *(f32x4*)(z0 + b*512 + (nq - 512)) = zz;
                        }
                    }
                }
            }
        } else {
            if (ss >= 1){
                f32x4 acc[4];
                #pragma unroll
                for (int nt = 0; nt < 4; ++nt) acc[nt] = f32x4{0.f,0.f,0.f,0.f};
                #pragma unroll
                for (int k = 0; k < 32; ++k){
                    s16x8 bv[4];
                    #pragma unroll
                    for (int nt = 0; nt < 4; ++nt){
                        const int row = nt*16 + ln;
                        bv[nt] = *(const s16x8*)(smem + ((row*2048 + k*64 + kg*16) ^ ((row & 7) << 4)));
                    }
                    #pragma unroll
                    for (int nt = 0; nt < 4; ++nt)
                        acc[nt] = __builtin_amdgcn_mfma_f32_16x16x32_bf16(wA[k], bv[nt], acc[nt], 0, 0, 0);
                }
                const int nq = n0A + kg*4;
                #pragma unroll
                for (int nt = 0; nt < 4; ++nt){
                    const int b = nt*16 + ln;
                    if (nq < 512){
                        union { ull u; unsigned short s[4]; } h;
                        h.u = *(const ull*)(smem + ((b*2048 + (512 + nq)*2) ^ ((b & 7) << 4)));
                        float rv[4];
                        #pragma unroll
                        for (int r = 0; r < 4; ++r)
                            rv[r] = sigm(acc[nt][r] + biasA1[r]) * bf2f(h.s[r]);
                        *(ull*)(rh1 + b*512 + nq) = pack4bf(rv);
                    } else if (nq < 1024){
                        float sg[4];
                        #pragma unroll
                        for (int r = 0; r < 4; ++r)
                            sg[r] = sigm(acc[nt][r] + biasA1[r]);
                        f32x4 zz = {sg[0], sg[1], sg[2], sg[3]};
                        *(f32x4*)(z1 + b*512 + (nq - 512)) = zz;
                    } else {
                        *(f32x4*)(P3 + b*512 + (nq - 1024)) = acc[nt];
                    }
                }
            }
        }
        ++gen; gsync(flags, rank, gen);

        // ===================== phase B: S2(ss) || S4(ss-1) ==================
        // blocks 0-7 stage rh0, blocks 8-15 stage rh1 (pitch 1024, swizzled)
        if (rank < 16){
            const int4* src = (const int4*)(rank < 8 ? rh0 : rh1);   // 4096 int4
            int4 t[16];
            #pragma unroll
            for (int j = 0; j < 16; ++j) t[j] = src[tid + j*256];
            #pragma unroll
            for (int j = 0; j < 16; ++j){
                const int c = tid + j*256;
                *(int4*)(smem + ((c*16) ^ (((c >> 6) & 7) << 4))) = t[j];
            }
        }
        __syncthreads();
        if (roleS1){
            if (ss < SEQ){
                const int t = ss;
                const int nq = n0B + kg*4;
                ull wxv[4]; f32x4 zv[4], hpv[4];           // prefetch epilogue operands
                #pragma unroll
                for (int nt = 0; nt < 4; ++nt){
                    const int b = nt*16 + ln;
                    wxv[nt] = *(const ull*)(WX0 + (long long)(t*64 + b)*1536 + 1024 + nq);
                    zv[nt]  = *(const f32x4*)(z0 + b*512 + nq);
                    hpv[nt] = *(const f32x4*)(HHf + b*1024 + nq);
                }
                f32x4 acc[4];
                #pragma unroll
                for (int nt = 0; nt < 4; ++nt) acc[nt] = f32x4{0.f,0.f,0.f,0.f};
                #pragma unroll
                for (int k = 0; k < 16; ++k){
                    s16x8 bv[4];
                    #pragma unroll
                    for (int nt = 0; nt < 4; ++nt){
                        const int row = nt*16 + ln;
                        bv[nt] = *(const s16x8*)(smem + ((row*1024 + k*64 + kg*16) ^ ((row & 7) << 4)));
                    }
                    #pragma unroll
                    for (int nt = 0; nt < 4; ++nt)
                        acc[nt] = __builtin_amdgcn_mfma_f32_16x16x32_bf16(wB[k], bv[nt], acc[nt], 0, 0, 0);
                }
                #pragma unroll
                for (int nt = 0; nt < 4; ++nt){
                    const int b = nt*16 + ln;
                    union { ull u; unsigned short s[4]; } wx; wx.u = wxv[nt];
                    float hn[4];
                    #pragma unroll
                    for (int r = 0; r < 4; ++r){
                        float pre = acc[nt][r] + bf2f(wx.s[r]) + biasB[r];
                        float ht = tanh_fast(pre);
                        hn[r] = (1.0f - zv[nt][r])*hpv[nt][r] + zv[nt][r]*ht;
                    }
                    f32x4 hv = {hn[0], hn[1], hn[2], hn[3]};
                    *(f32x4*)(HHf + b*1024 + nq) = hv;
                    *(ull*)(HHbf + b*1024 + nq) = pack4bf(hn);
                }
            }
        } else if (roleS4){
            if (ss >= 1){
                const int t = ss - 1;
                const int nq = n0B + kg*4;
                f32x4 ppv[4], zv[4], hpv[4];
                #pragma unroll
                for (int nt = 0; nt < 4; ++nt){
                    const int b = nt*16 + ln;
                    ppv[nt] = *(const f32x4*)(P3 + b*512 + nq);
                    zv[nt]  = *(const f32x4*)(z1 + b*512 + nq);
                    hpv[nt] = *(const f32x4*)(HHf + b*1024 + 512 + nq);
                }
                f32x4 acc[4];
                #pragma unroll
                for (int nt = 0; nt < 4; ++nt) acc[nt] = f32x4{0.f,0.f,0.f,0.f};
                #pragma unroll
                for (int k = 0; k < 16; ++k){
                    s16x8 bv[4];
                    #pragma unroll
                    for (int nt = 0; nt < 4; ++nt){
                        const int row = nt*16 + ln;
                        bv[nt] = *(const s16x8*)(smem + ((row*1024 + k*64 + kg*16) ^ ((row & 7) << 4)));
                    }
                    #pragma unroll
                    for (int nt = 0; nt < 4; ++nt)
                        acc[nt] = __builtin_amdgcn_mfma_f32_16x16x32_bf16(wB[k], bv[nt], acc[nt], 0, 0, 0);
                }
                #pragma unroll
                for (int nt = 0; nt < 4; ++nt){
                    const int b = nt*16 + ln;
                    float hn[4];
                    #pragma unroll
                    for (int r = 0; r < 4; ++r){
                        float pre = acc[nt][r] + ppv[nt][r] + biasB[r];
                        float ht = tanh_fast(pre);
                        hn[r] = (1.0f - zv[nt][r])*hpv[nt][r] + zv[nt][r]*ht;
                    }
                    f32x4 hv = {hn[0], hn[1], hn[2], hn[3]};
                    *(f32x4*)(HHf + b*1024 + 512 + nq) = hv;
                    *(ull*)(HHbf + b*1024 + 512 + nq) = pack4bf(hn);
                    *(ull*)(H2bf + (long long)(t*64 + b)*512 + nq) = pack4bf(hn);
                }
            }
        }
        ++gen; gsync(flags, rank, gen);
    }

    // h_final tail: out[(l*64+b)*512 + j] = HHf[b*1024 + l*512 + j]
    for (int c = rank*256 + tid; c < 16384; c += NPART*256){
        f32x4 v = *(const f32x4*)(HHf + c*4);
        int b = c >> 8, cc = c & 255, l = cc >> 7, j = (cc & 127) << 2;
        *(f32x4*)(outTail + l*32768 + b*512 + j) = v;
    }
}

// ---------------------------------------------------------------- launch ----
extern "C" void kernel_launch(void* const* d_in, const int* in_sizes, int n_in,
                              void* d_out, int out_size, void* d_ws, size_t ws_size,
                              hipStream_t stream)
{
    const int*   inputs = (const int*)d_in[0];
    const float* hidden = (const float*)d_in[1];
    const float* emb    = (const float*)d_in[2];
    const float* Wx     = (const float*)d_in[3];
    const float* Uh     = (const float*)d_in[4];
    const float* Uht    = (const float*)d_in[5];
    const float* b_rzh  = (const float*)d_in[6];
    const float* dec_w  = (const float*)d_in[7];
    const float* dec_b  = (const float*)d_in[8];
    float* out = (float*)d_out;

    char* w = (char*)d_ws;
    size_t off = 0;
    auto alloc = [&](size_t bytes)->char*{
        char* p = w + off; off = (off + bytes + 255) & ~(size_t)255; return p;
    };
    unsigned short* emb_bf = (unsigned short*)alloc(4096LL*512*2);
    unsigned short* WxT0   = (unsigned short*)alloc(1536LL*512*2);
    unsigned short* WX0    = (unsigned short*)alloc(4096LL*1536*2);
    unsigned short* UhT0   = (unsigned short*)alloc(1024LL*512*2);
    unsigned short* UhtT0  = (unsigned short*)alloc(512LL*512*2);
    unsigned short* B3T    = (unsigned short*)alloc(1536LL*1024*2);
    unsigned short* UhtT1  = (unsigned short*)alloc(512LL*512*2);
    unsigned short* decpad = (unsigned short*)alloc(10112LL*512*2);
    float*          HH     = (float*)alloc(65536*4);
    unsigned short* HHbf   = (unsigned short*)alloc(65536*2);
    unsigned short* rh0    = (unsigned short*)alloc(64*512*2);
    unsigned short* rh1    = (unsigned short*)alloc(64*512*2);
    float*          z0     = (float*)alloc(64*512*4);
    float*          z1     = (float*)alloc(64*512*4);
    float*          P3     = (float*)alloc(64*512*4);
    unsigned short* H2bf   = (unsigned short*)alloc(4096LL*512*2);
    unsigned int*   barzone= (unsigned int*)alloc(8192);
    if (off > ws_size) return;  // workspace too small: fail loudly via absmax

    prep_kernel<<<1024, 256, 0, stream>>>(inputs, hidden, emb, Wx, Uh, Uht, dec_w,
        emb_bf, WxT0, UhT0, UhtT0, B3T, UhtT1, decpad, HH, HHbf, barzone);

    // WX0 = embed @ Wx0  (M=4096, N=1536, K=512), bf16 out
    gemm128<<<dim3(32*12), 256, 0, stream>>>(emb_bf, WxT0, 4096, 1536, 512,
        0, nullptr, WX0, nullptr, 1536);

    // persistent recurrent kernel: 256 blocks, 32 workers on one XCD,
    // register-resident weights
    gru_kernel<<<dim3(256), 256, 0, stream>>>(HH, HHbf, UhT0, UhtT0, B3T, UhtT1,
        WX0, rh0, rh1, z0, z1, P3, H2bf, b_rzh, out + 40960000, barzone);

    // decoder: logits = H2 @ dec_w^T + dec_b  (M=4096, N=10112 padded, K=512)
    gemm128<<<dim3(32*79), 256, 0, stream>>>(H2bf, decpad, 4096, 10112, 512,
        1, out, nullptr, dec_b, 10000);
}

// Round 9
// 2022.932 us; speedup vs baseline: 1.8674x; 1.8674x over previous
//
#include <hip/hip_runtime.h>
#include <hip/hip_bf16.h>

// GRU: SEQ=64, BATCH=64, HID=EMB=512, VOCAB=10000, LAYERS=2
// Outputs: logits (64,64,10000) f32 then h_final (2,64,512) f32, concat flat.

#define SEQ 64
#define NPX 16     // worker blocks per XCD
#define NPART 32   // total workers (layer 0 on XCD-A, layer 1 on XCD-B)

typedef short s16x8 __attribute__((ext_vector_type(8)));   // 8 bf16 (4 VGPRs)
typedef float f32x4 __attribute__((ext_vector_type(4)));
typedef int   i32x4 __attribute__((ext_vector_type(4)));
typedef unsigned long long ull;

static __device__ __forceinline__ unsigned short f2bf(float f){
    unsigned int u = __float_as_uint(f);
    return (unsigned short)((u + 0x7FFFu + ((u >> 16) & 1u)) >> 16);  // RNE
}
static __device__ __forceinline__ float bf2f(unsigned short s){
    return __uint_as_float(((unsigned int)s) << 16);
}
static __device__ __forceinline__ float sigm(float x){
    return __fdividef(1.0f, 1.0f + __expf(-x));
}
static __device__ __forceinline__ float tanh_fast(float x){
    float ax = fabsf(x);
    float e = __expf(-2.0f * ax);
    float r = __fdividef(1.0f - e, 1.0f + e);
    return copysignf(r, x);
}
static __device__ __forceinline__ ull pack4bf(const float v[4]){
    union { ull u; unsigned short s[4]; } x;
    x.s[0]=f2bf(v[0]); x.s[1]=f2bf(v[1]); x.s[2]=f2bf(v[2]); x.s[3]=f2bf(v[3]);
    return x.u;
}
// sc0 sc1 = MALL-coherent cross-XCD path (R4/R6-proven). Batched issue, one wait.
#define SC_LD16_NW(T,A) \
  asm volatile("global_load_dwordx4 %0, %1, off sc0 sc1" : "=&v"(T) : "v"(A) : "memory")
#define SC_WAIT() asm volatile("s_waitcnt vmcnt(0)" ::: "memory")
static __device__ __forceinline__ void sc_st8(void* p, ull v){
    asm volatile("global_store_dwordx2 %0, %1, off sc0 sc1" :: "v"(p), "v"(v) : "memory");
}

// ---------------------------------------------------------------- prep ------
__global__ void prep_kernel(const int* __restrict__ inputs, const float* __restrict__ hidden,
    const float* __restrict__ emb, const float* __restrict__ Wx, const float* __restrict__ Uh,
    const float* __restrict__ Uht, const float* __restrict__ dec_w,
    unsigned short* __restrict__ emb_bf, unsigned short* __restrict__ WxT0,
    unsigned short* __restrict__ UhT0, unsigned short* __restrict__ UhtT0,
    unsigned short* __restrict__ B3T, unsigned short* __restrict__ UhtT1,
    unsigned short* __restrict__ decpad,
    float* __restrict__ HH, unsigned short* __restrict__ HHbf,
    unsigned short* __restrict__ H0m, unsigned int* __restrict__ barzone)
{
    const long long stride = (long long)gridDim.x * blockDim.x;
    const long long t0 = (long long)blockIdx.x * blockDim.x + threadIdx.x;
    for (long long i = t0; i < 4096LL*512; i += stride){
        int r = (int)(i >> 9), k = (int)(i & 511);
        emb_bf[i] = f2bf(emb[(long long)inputs[r]*512 + k]);
    }
    for (long long i = t0; i < 1536LL*512; i += stride){
        int n = (int)(i >> 9), k = (int)(i & 511);
        WxT0[i] = f2bf(Wx[(long long)k*1536 + n]);
    }
    for (long long i = t0; i < 1024LL*512; i += stride){
        int n = (int)(i >> 9), k = (int)(i & 511);
        UhT0[i] = f2bf(Uh[(long long)k*1024 + n]);
    }
    for (long long i = t0; i < 512LL*512; i += stride){
        int n = (int)(i >> 9), k = (int)(i & 511);
        UhtT0[i] = f2bf(Uht[(long long)k*512 + n]);
    }
    for (long long i = t0; i < 1536LL*1024; i += stride){
        int n = (int)(i >> 10), k2 = (int)(i & 1023);
        float v;
        if (k2 < 512) v = Wx[(long long)(512 + k2)*1536 + n];          // Wx[1][k2][n]
        else { int k = k2 - 512; v = (n < 1024) ? Uh[(long long)(512 + k)*1024 + n] : 0.0f; }
        B3T[i] = f2bf(v);
    }
    for (long long i = t0; i < 512LL*512; i += stride){
        int n = (int)(i >> 9), k = (int)(i & 511);
        UhtT1[i] = f2bf(Uht[(long long)(512 + k)*512 + n]);
    }
    for (long long i = t0; i < 10112LL*512; i += stride){
        int n = (int)(i >> 9), k = (int)(i & 511);
        decpad[i] = (n < 10000) ? f2bf(dec_w[(long long)n*512 + k]) : (unsigned short)0;
    }
    for (long long i = t0; i < 65536; i += stride){
        int b = (int)(i >> 10), c = (int)(i & 1023);
        int l = c >> 9, j = c & 511;
        float v = hidden[((long long)l*64 + b)*512 + j];
        HH[i] = v; HHbf[i] = f2bf(v);                                  // HH[b][l*512+j]
    }
    for (long long i = t0; i < 32768; i += stride){
        int b = (int)(i >> 9), j = (int)(i & 511);
        H0m[i] = f2bf(hidden[(long long)b*512 + j]);                   // h0 MALL mirror
    }
    for (long long i = t0; i < 2048; i += stride) barzone[i] = 0u;
}

// ------------------------------------------------- tiled 128x128 bf16 GEMM --
__global__ __launch_bounds__(256) void gemm128(const unsigned short* __restrict__ A,
    const unsigned short* __restrict__ BT, int M, int N, int K, int mode,
    float* __restrict__ outF, unsigned short* __restrict__ outB,
    const float* __restrict__ bias, int Nreal)
{
    __shared__ unsigned short Ash[128*32];
    __shared__ unsigned short Bsh[128*32];
    const int nT = N >> 7;
    const int mb = blockIdx.x / nT, nb = blockIdx.x % nT;
    const int tid = threadIdx.x;
    const int lane = tid & 63, wId = tid >> 6;
    const int wm = wId >> 1, wn = wId & 1;
    const int ln = lane & 15, kg = lane >> 4;
    f32x4 acc[4][4];
    #pragma unroll
    for (int mt = 0; mt < 4; ++mt)
        #pragma unroll
        for (int nt = 0; nt < 4; ++nt) acc[mt][nt] = f32x4{0.f,0.f,0.f,0.f};

    for (int kc = 0; kc < K; kc += 32){
        #pragma unroll
        for (int it = 0; it < 2; ++it){
            int flat = it*256 + tid;
            int row = flat >> 2, kq = flat & 3;
            *(int4*)(&Ash[flat*8]) = *(const int4*)(A + (long long)(mb*128 + row)*K + kc + kq*8);
            *(int4*)(&Bsh[flat*8]) = *(const int4*)(BT + (long long)(nb*128 + row)*K + kc + kq*8);
        }
        __syncthreads();
        s16x8 af[4], bfv[4];
        #pragma unroll
        for (int mt = 0; mt < 4; ++mt) af[mt]  = *(const s16x8*)(&Ash[(wm*64 + mt*16 + ln)*32 + kg*8]);
        #pragma unroll
        for (int nt = 0; nt < 4; ++nt) bfv[nt] = *(const s16x8*)(&Bsh[(wn*64 + nt*16 + ln)*32 + kg*8]);
        #pragma unroll
        for (int mt = 0; mt < 4; ++mt)
            #pragma unroll
            for (int nt = 0; nt < 4; ++nt)
                acc[mt][nt] = __builtin_amdgcn_mfma_f32_16x16x32_bf16(af[mt], bfv[nt], acc[mt][nt], 0, 0, 0);
        __syncthreads();
    }
    #pragma unroll
    for (int mt = 0; mt < 4; ++mt)
        #pragma unroll
        for (int nt = 0; nt < 4; ++nt)
            #pragma unroll
            for (int r = 0; r < 4; ++r){
                int row = mb*128 + wm*64 + mt*16 + kg*4 + r;   // C/D: col=lane&15, row=(lane>>4)*4+reg
                int col = nb*128 + wn*64 + nt*16 + ln;
                float v = acc[mt][nt][r];
                if (mode == 0){
                    outB[(long long)row*N + col] = f2bf(v);
                } else {
                    if (col < Nreal) outF[(long long)row*Nreal + col] = v + bias[col];
                }
            }
}

// -------------------------------------------------------- persistent GRU ----
// Layer 0 on XCD-A, layer 1 on XCD-B: each XCD's weights fit its 4MB L2.
// Intra-XCD state: plain cached loads/stores (R7-proven: vmcnt drain -> L2,
// buffer_inv -> L1 freshness). Cross-XCD: h0 mirror in MALL via sc0sc1
// (R4/R6-proven). Barrier: per-rank MALL flag lines, bounded poll (hang-proof).
static __device__ __forceinline__ void gsync(unsigned int* flags, int rank, unsigned gen){
    asm volatile("s_waitcnt vmcnt(0)" ::: "memory");   // all stores visible
    __syncthreads();
    if (threadIdx.x < 64){
        if (threadIdx.x == 0){
            asm volatile("global_store_dword %0, %1, off sc0 sc1"
                         :: "v"(flags + rank*32), "v"(gen) : "memory");
        }
        const unsigned int* p = flags + (threadIdx.x & (NPART-1))*32;
        unsigned v; int it = 0;
        do {
            asm volatile("global_load_dword %0, %1, off sc0 sc1\n\ts_waitcnt vmcnt(0)"
                         : "=v"(v) : "v"(p) : "memory");
        } while (__ballot(v >= gen) != ~0ull && ++it < (1 << 20));
    }
    __syncthreads();
    asm volatile("buffer_inv" ::: "memory");           // L1 invalidate (fresh L2 reads)
}

// Wave-tile GEMM: D[16 n][64 b]. A = weight slice (N,K) global (L2-resident),
// B = 4 b-fragments from XOR-swizzled LDS. C/D: col(b)=lane&15, row(n)=(lane>>4)*4+reg.
template<int KIT, int PITCH>
static __device__ __forceinline__ void mmTile(const unsigned short* __restrict__ W,
    const char* __restrict__ lds, int ln, int kg, f32x4 acc[4])
{
    constexpr int K = KIT * 32;
    #pragma unroll
    for (int nt = 0; nt < 4; ++nt) acc[nt] = f32x4{0.f,0.f,0.f,0.f};
    #pragma unroll 4
    for (int k = 0; k < KIT; ++k){
        s16x8 bv[4];
        #pragma unroll
        for (int nt = 0; nt < 4; ++nt){
            const int row = nt*16 + ln;
            bv[nt] = *(const s16x8*)(lds + ((row*PITCH + k*64 + kg*16) ^ ((row & 7) << 4)));
        }
        s16x8 av = *(const s16x8*)(W + ln*K + k*32 + kg*8);
        #pragma unroll
        for (int nt = 0; nt < 4; ++nt)
            acc[nt] = __builtin_amdgcn_mfma_f32_16x16x32_bf16(av, bv[nt], acc[nt], 0, 0, 0);
    }
}

__global__ __launch_bounds__(512, 1) void gru_kernel(
    float* __restrict__ HHf, unsigned short* __restrict__ HHbf,
    const unsigned short* __restrict__ UhT0, const unsigned short* __restrict__ UhtT0,
    const unsigned short* __restrict__ B3T,  const unsigned short* __restrict__ UhtT1,
    const unsigned short* __restrict__ WX0,
    unsigned short* __restrict__ rh0, unsigned short* __restrict__ rh1,
    float* __restrict__ z0, float* __restrict__ z1, float* __restrict__ P3,
    unsigned short* __restrict__ H2bf, unsigned short* __restrict__ H0m,
    const float* __restrict__ b_rzh,
    float* __restrict__ outTail, unsigned int* __restrict__ barzone)
{
    __shared__ __align__(16) char smem[131072];   // 128 KB -> 1 block/CU
    __shared__ int s_rank;
    const int tid = threadIdx.x, lane = tid & 63, wv = tid >> 6;  // 8 waves
    const int ln = lane & 15, kg = lane >> 4;

    // ---- elect 16 workers on each of TWO distinct XCDs (1 block/CU -> 32/XCD)
    if (tid == 0){
        unsigned xcc;
        asm volatile("s_getreg_b32 %0, hwreg(HW_REG_XCC_ID)" : "=s"(xcc));
        unsigned my = (xcc & 15u) + 1u;
        int r = -1;
        unsigned a = atomicCAS(barzone + 1, 0u, my);
        if (a == 0u) a = my;
        if (my == a){
            int q = (int)atomicAdd(barzone + 2, 1u);
            if (q < NPX) r = q;                      // XCD-A: ranks 0..15 (layer 0)
        } else {
            unsigned b = atomicCAS(barzone + 3, 0u, my);
            if (b == 0u) b = my;
            if (my == b){
                int q = (int)atomicAdd(barzone + 4, 1u);
                if (q < NPX) r = NPX + q;            // XCD-B: ranks 16..31 (layer 1)
            }
        }
        s_rank = r;
    }
    __syncthreads();
    const int rank = s_rank;
    if (rank < 0) return;                            // non-workers exit

    unsigned int* flags = barzone + 256;
    const bool x0 = (rank < NPX);
    const int lr = rank & 15;                        // local rank in XCD
    const int lw = lr*8 + wv;                        // local wave id 0..127
    const float* b0 = b_rzh;
    const float* b1 = b_rzh + 1536;
    unsigned gen = 0;

    // per-wave bias vectors (clamped addresses keep inactive waves in-bounds)
    const int n0A = lw * 16;                         // phase-A tile base
    const int n0B = (lw < 32 ? lw : 0) * 16;         // phase-B tile base
    const int nA = (n0A < (x0 ? 1024 : 1520)) ? n0A : 0;
    f32x4 biasA = x0 ? *(const f32x4*)(b0 + nA + kg*4)
                     : *(const f32x4*)(b1 + nA + kg*4);
    f32x4 biasB = x0 ? *(const f32x4*)(b0 + 1024 + n0B + kg*4)
                     : *(const f32x4*)(b1 + 1024 + n0B + kg*4);

    for (int ss = 0; ss <= SEQ; ++ss){
        // ===================== phase A: S1(ss)@XCD-A || S3(ss-1)@XCD-B ======
        if (x0){
            if (lr < 8){   // stage h0bf [64][512] local -> LDS pitch 1024, swizzled
                const int4* src = (const int4*)HHbf;
                int4 t[8];
                #pragma unroll
                for (int j = 0; j < 8; ++j){
                    const int c = tid + j*512, b = c >> 6, col = c & 63;
                    t[j] = src[(b << 7) + col];
                }
                #pragma unroll
                for (int j = 0; j < 8; ++j){
                    const int c = tid + j*512, b = c >> 6, col = c & 63;
                    *(int4*)(smem + ((b*1024 + col*16) ^ ((b & 7) << 4))) = t[j];
                }
            }
        } else {
            if (lr < 12){  // stage H [64][1024]: h0 from MALL mirror (sc), h1 local
                i32x4 t0[8]; int4 t1[8];
                const char* srcm = (const char*)H0m;
                const int4* srch = (const int4*)HHbf;
                #pragma unroll
                for (int j = 0; j < 8; ++j){
                    const int c = tid + j*512, b = c >> 6, col = c & 63;
                    SC_LD16_NW(t0[j], srcm + (long long)c*16);
                    t1[j] = srch[(b << 7) + 64 + col];
                }
                SC_WAIT();
                #pragma unroll
                for (int j = 0; j < 8; ++j){
                    const int c = tid + j*512, b = c >> 6, col = c & 63;
                    *(i32x4*)(smem + ((b*2048 + col*16) ^ ((b & 7) << 4))) = t0[j];
                    *(int4*)(smem + ((b*2048 + 1024 + col*16) ^ ((b & 7) << 4))) = t1[j];
                }
            }
        }
        __syncthreads();
        if (x0){
            if (lw < 64 && ss < SEQ){
                // ---- S1 job: n0A of 1024 (uh = h0 @ Uh0), K=512
                const int t = ss;
                const int nq = n0A + kg*4;
                ull wxv[4];
                #pragma unroll
                for (int nt = 0; nt < 4; ++nt)
                    wxv[nt] = *(const ull*)(WX0 + (long long)(t*64 + nt*16 + ln)*1536 + nq);
                f32x4 acc[4];
                mmTile<16,1024>(UhT0 + n0A*512, smem, ln, kg, acc);
                #pragma unroll
                for (int nt = 0; nt < 4; ++nt){
                    const int b = nt*16 + ln;
                    union { ull u; unsigned short s[4]; } wx; wx.u = wxv[nt];
                    float sg[4];
                    #pragma unroll
                    for (int r = 0; r < 4; ++r)
                        sg[r] = sigm(acc[nt][r] + bf2f(wx.s[r]) + biasA[r]);
                    if (nq < 512){
                        union { ull u; unsigned short s[4]; } h;
                        h.u = *(const ull*)(smem + ((b*1024 + nq*2) ^ ((b & 7) << 4)));
                        float rv[4];
                        #pragma unroll
                        for (int r = 0; r < 4; ++r) rv[r] = sg[r] * bf2f(h.s[r]);
                        *(ull*)(rh0 + b*512 + nq) = pack4bf(rv);
                    } else {
                        f32x4 zz = {sg[0], sg[1], sg[2], sg[3]};
                        *(f32x4*)(z0 + b*512 + (nq - 512)) = zz;
                    }
                }
            }
        } else {
            if (lw < 96 && ss >= 1){
                // ---- S3 job: n0A of 1536 ([h0|h1] @ B3T), K=1024
                f32x4 acc[4];
                mmTile<32,2048>(B3T + (long long)n0A*1024, smem, ln, kg, acc);
                const int nq = n0A + kg*4;
                #pragma unroll
                for (int nt = 0; nt < 4; ++nt){
                    const int b = nt*16 + ln;
                    if (nq < 512){
                        union { ull u; unsigned short s[4]; } h;
                        h.u = *(const ull*)(smem + ((b*2048 + (512 + nq)*2) ^ ((b & 7) << 4)));
                        float rv[4];
                        #pragma unroll
                        for (int r = 0; r < 4; ++r)
                            rv[r] = sigm(acc[nt][r] + biasA[r]) * bf2f(h.s[r]);
                        *(ull*)(rh1 + b*512 + nq) = pack4bf(rv);
                    } else if (nq < 1024){
                        float sg[4];
                        #pragma unroll
                        for (int r = 0; r < 4; ++r)
                            sg[r] = sigm(acc[nt][r] + biasA[r]);
                        f32x4 zz = {sg[0], sg[1], sg[2], sg[3]};
                        *(f32x4*)(z1 + b*512 + (nq - 512)) = zz;
                    } else {
                        *(f32x4*)(P3 + b*512 + (nq - 1024)) = acc[nt];
                    }
                }
            }
        }
        ++gen; gsync(flags, rank, gen);

        // ===================== phase B: S2(ss)@XCD-A || S4(ss-1)@XCD-B ======
        if (lr < 4){      // stage rh [64][512] local -> LDS pitch 1024, swizzled
            const int4* src = (const int4*)(x0 ? rh0 : rh1);
            int4 t[8];
            #pragma unroll
            for (int j = 0; j < 8; ++j) t[j] = src[tid + j*512];
            #pragma unroll
            for (int j = 0; j < 8; ++j){
                const int c = tid + j*512;
                *(int4*)(smem + ((c*16) ^ (((c >> 6) & 7) << 4))) = t[j];
            }
        }
        __syncthreads();
        if (lw < 32){
            if (x0 && ss < SEQ){
                // ---- S2: h0 update, n0B of 512, K=512
                const int t = ss;
                const int nq = n0B + kg*4;
                ull wxv[4]; f32x4 zv[4], hpv[4];
                #pragma unroll
                for (int nt = 0; nt < 4; ++nt){
                    const int b = nt*16 + ln;
                    wxv[nt] = *(const ull*)(WX0 + (long long)(t*64 + b)*1536 + 1024 + nq);
                    zv[nt]  = *(const f32x4*)(z0 + b*512 + nq);
                    hpv[nt] = *(const f32x4*)(HHf + b*1024 + nq);
                }
                f32x4 acc[4];
                mmTile<16,1024>(UhtT0 + n0B*512, smem, ln, kg, acc);
                #pragma unroll
                for (int nt = 0; nt < 4; ++nt){
                    const int b = nt*16 + ln;
                    union { ull u; unsigned short s[4]; } wx; wx.u = wxv[nt];
                    float hn[4];
                    #pragma unroll
                    for (int r = 0; r < 4; ++r){
                        float pre = acc[nt][r] + bf2f(wx.s[r]) + biasB[r];
                        float ht = tanh_fast(pre);
                        hn[r] = (1.0f - zv[nt][r])*hpv[nt][r] + zv[nt][r]*ht;
                    }
                    f32x4 hv = {hn[0], hn[1], hn[2], hn[3]};
                    *(f32x4*)(HHf + b*1024 + nq) = hv;
                    ull pb = pack4bf(hn);
                    *(ull*)(HHbf + b*1024 + nq) = pb;      // local (XCD-A consumers)
                    sc_st8(H0m + b*512 + nq, pb);          // MALL mirror (XCD-B)
                }
            } else if (!x0 && ss >= 1){
                // ---- S4: h1 update + H2bf, n0B of 512, K=512
                const int t = ss - 1;
                const int nq = n0B + kg*4;
                f32x4 ppv[4], zv[4], hpv[4];
                #pragma unroll
                for (int nt = 0; nt < 4; ++nt){
                    const int b = nt*16 + ln;
                    ppv[nt] = *(const f32x4*)(P3 + b*512 + nq);
                    zv[nt]  = *(const f32x4*)(z1 + b*512 + nq);
                    hpv[nt] = *(const f32x4*)(HHf + b*1024 + 512 + nq);
                }
                f32x4 acc[4];
                mmTile<16,1024>(UhtT1 + n0B*512, smem, ln, kg, acc);
                #pragma unroll
                for (int nt = 0; nt < 4; ++nt){
                    const int b = nt*16 + ln;
                    float hn[4];
                    #pragma unroll
                    for (int r = 0; r < 4; ++r){
                        float pre = acc[nt][r] + ppv[nt][r] + biasB[r];
                        float ht = tanh_fast(pre);
                        hn[r] = (1.0f - zv[nt][r])*hpv[nt][r] + zv[nt][r]*ht;
                    }
                    f32x4 hv = {hn[0], hn[1], hn[2], hn[3]};
                    *(f32x4*)(HHf + b*1024 + 512 + nq) = hv;
                    ull pb = pack4bf(hn);
                    *(ull*)(HHbf + b*1024 + 512 + nq) = pb;
                    *(ull*)(H2bf + (long long)(t*64 + b)*512 + nq) = pb;
                }
            }
        }
        ++gen; gsync(flags, rank, gen);
    }

    // h_final tail: each XCD writes its own layer's half (local L2 reads).
    // out[(l*64+b)*512 + j] = HHf[b*1024 + l*512 + j]
    {
        const int base = x0 ? 0 : 512;
        const int obase = x0 ? 0 : 32768;
        for (int c = lr*512 + tid; c < 8192; c += NPX*512){
            const int b = c >> 7, j4 = c & 127;
            f32x4 v = *(const f32x4*)(HHf + b*1024 + base + j4*4);
            *(f32x4*)(outTail + obase + b*512 + j4*4) = v;
        }
    }
}

// ---------------------------------------------------------------- launch ----
extern "C" void kernel_launch(void* const* d_in, const int* in_sizes, int n_in,
                              void* d_out, int out_size, void* d_ws, size_t ws_size,
                              hipStream_t stream)
{
    const int*   inputs = (const int*)d_in[0];
    const float* hidden = (const float*)d_in[1];
    const float* emb    = (const float*)d_in[2];
    const float* Wx     = (const float*)d_in[3];
    const float* Uh     = (const float*)d_in[4];
    const float* Uht    = (const float*)d_in[5];
    const float* b_rzh  = (const float*)d_in[6];
    const float* dec_w  = (const float*)d_in[7];
    const float* dec_b  = (const float*)d_in[8];
    float* out = (float*)d_out;

    char* w = (char*)d_ws;
    size_t off = 0;
    auto alloc = [&](size_t bytes)->char*{
        char* p = w + off; off = (off + bytes + 255) & ~(size_t)255; return p;
    };
    unsigned short* emb_bf = (unsigned short*)alloc(4096LL*512*2);
    unsigned short* WxT0   = (unsigned short*)alloc(1536LL*512*2);
    unsigned short* WX0    = (unsigned short*)alloc(4096LL*1536*2);
    unsigned short* UhT0   = (unsigned short*)alloc(1024LL*512*2);
    unsigned short* UhtT0  = (unsigned short*)alloc(512LL*512*2);
    unsigned short* B3T    = (unsigned short*)alloc(1536LL*1024*2);
    unsigned short* UhtT1  = (unsigned short*)alloc(512LL*512*2);
    unsigned short* decpad = (unsigned short*)alloc(10112LL*512*2);
    float*          HH     = (float*)alloc(65536*4);
    unsigned short* HHbf   = (unsigned short*)alloc(65536*2);
    unsigned short* H0m    = (unsigned short*)alloc(64*512*2);
    unsigned short* rh0    = (unsigned short*)alloc(64*512*2);
    unsigned short* rh1    = (unsigned short*)alloc(64*512*2);
    float*          z0     = (float*)alloc(64*512*4);
    float*          z1     = (float*)alloc(64*512*4);
    float*          P3     = (float*)alloc(64*512*4);
    unsigned short* H2bf   = (unsigned short*)alloc(4096LL*512*2);
    unsigned int*   barzone= (unsigned int*)alloc(8192);
    if (off > ws_size) return;  // workspace too small: fail loudly via absmax

    prep_kernel<<<1024, 256, 0, stream>>>(inputs, hidden, emb, Wx, Uh, Uht, dec_w,
        emb_bf, WxT0, UhT0, UhtT0, B3T, UhtT1, decpad, HH, HHbf, H0m, barzone);

    // WX0 = embed @ Wx0  (M=4096, N=1536, K=512), bf16 out
    gemm128<<<dim3(32*12), 256, 0, stream>>>(emb_bf, WxT0, 4096, 1536, 512,
        0, nullptr, WX0, nullptr, 1536);

    // persistent recurrent kernel: 256 blocks, 16 workers on each of 2 XCDs
    gru_kernel<<<dim3(256), 512, 0, stream>>>(HH, HHbf, UhT0, UhtT0, B3T, UhtT1,
        WX0, rh0, rh1, z0, z1, P3, H2bf, H0m, b_rzh, out + 40960000, barzone);

    // decoder: logits = H2 @ dec_w^T + dec_b  (M=4096, N=10112 padded, K=512)
    gemm128<<<dim3(32*79), 256, 0, stream>>>(H2bf, decpad, 4096, 10112, 512,
        1, out, nullptr, dec_b, 10000);
}